// Round 1
// baseline (1243.702 us; speedup 1.0000x reference)
//
#include <hip/hip_runtime.h>
#include <hip/hip_bf16.h>
#include <cstdint>
#include <cstddef>

#define T_N 2048
#define D_N 2048
#define F_N 1024
#define E_N 32

typedef short short8 __attribute__((ext_vector_type(8)));
typedef float f32x4 __attribute__((ext_vector_type(4)));

__device__ __forceinline__ float bf2f(unsigned short u) {
  union { unsigned int i; float f; } c; c.i = ((unsigned int)u) << 16; return c.f;
}
__device__ __forceinline__ unsigned short f2bf(float f) {
  unsigned int r;
  asm("v_cvt_pk_bf16_f32 %0, %1, %1" : "=v"(r) : "v"(f));
  return (unsigned short)(r & 0xffffu);
}
// Load 8 contiguous elements at element-index eidx as packed bf16 (uint4).
// m=1: source is fp32 (convert via HW packed cvt); m=0: source is bf16 (raw).
__device__ __forceinline__ uint4 load8_as_bf16(const void* p, size_t eidx, int m) {
  uint4 r;
  if (m) {
    const float* f = (const float*)p + eidx;
    float4 a = *(const float4*)f;
    float4 b = *(const float4*)(f + 4);
    asm("v_cvt_pk_bf16_f32 %0, %1, %2" : "=v"(r.x) : "v"(a.x), "v"(a.y));
    asm("v_cvt_pk_bf16_f32 %0, %1, %2" : "=v"(r.y) : "v"(a.z), "v"(a.w));
    asm("v_cvt_pk_bf16_f32 %0, %1, %2" : "=v"(r.z) : "v"(b.x), "v"(b.y));
    asm("v_cvt_pk_bf16_f32 %0, %1, %2" : "=v"(r.w) : "v"(b.z), "v"(b.w));
  } else {
    r = *(const uint4*)((const unsigned short*)p + eidx);
  }
  return r;
}
__device__ __forceinline__ float loadf(const void* p, size_t eidx, int m) {
  return m ? ((const float*)p)[eidx] : bf2f(((const unsigned short*)p)[eidx]);
}

// ---------------- init: zero counts/nt_total + detect input dtype ----------------
// head layout (ints): [0..31]=counts, [32]=nt_total, [48]=mode (1=fp32, 0=bf16)
__global__ __launch_bounds__(64) void init_kernel(const void* X, int* head) {
  int lane = threadIdx.x;
  if (lane <= 32) head[lane] = 0;
  float x = ((const float*)X)[lane];
  float ax = fabsf(x);
  int ok = (ax < 100.f && ax > 1e-6f) ? 1 : 0;  // NaN -> false
  unsigned long long bal = __ballot(ok);
  if (lane == 0) head[48] = (__popcll(bal) >= 48) ? 1 : 0;
}

// ---------------- router: logits, top-2, renorm, bucket ----------------
__global__ __launch_bounds__(64) void router_kernel(
    const void* __restrict__ X, const void* __restrict__ GW, const int* __restrict__ mode,
    int* __restrict__ counts, int* __restrict__ ti_list, float* __restrict__ wt_list) {
  int t = blockIdx.x, lane = threadIdx.x;
  const int m = *mode;
  float acc[E_N];
#pragma unroll
  for (int e = 0; e < E_N; ++e) acc[e] = 0.f;
  for (int d0 = 0; d0 < D_N; d0 += 64) {
    float xv = loadf(X, (size_t)t * D_N + d0 + lane, m);
#pragma unroll
    for (int e = 0; e < E_N; ++e)
      acc[e] += xv * loadf(GW, (size_t)e * D_N + d0 + lane, m);
  }
#pragma unroll
  for (int e = 0; e < E_N; ++e) {
#pragma unroll
    for (int off = 32; off; off >>= 1) acc[e] += __shfl_xor(acc[e], off);
  }
  if (lane == 0) {
    float v0 = -1e30f, v1 = -1e30f; int i0 = 0, i1 = 0;
#pragma unroll
    for (int e = 0; e < E_N; ++e) {
      float v = acc[e];
      if (v > v0) { v1 = v0; i1 = i0; v0 = v; i0 = e; }
      else if (v > v1) { v1 = v; i1 = e; }
    }
    float e1 = __expf(v1 - v0);
    float w0 = 1.f / (1.f + e1);
    float w1 = e1 / (1.f + e1);
    int s0 = atomicAdd(&counts[i0], 1);
    ti_list[i0 * T_N + s0] = t * 2 + 0; wt_list[i0 * T_N + s0] = w0;
    int s1 = atomicAdd(&counts[i1], 1);
    ti_list[i1 * T_N + s1] = t * 2 + 1; wt_list[i1 * T_N + s1] = w1;
  }
}

// ---------------- compaction: pad-to-128 slots + tile table ----------------
__global__ __launch_bounds__(256) void compact_kernel(
    const int* __restrict__ counts, const int* __restrict__ ti_list,
    const float* __restrict__ wt_list,
    int* __restrict__ mt_e, int* __restrict__ mt_sb, int* __restrict__ nt_total,
    int* __restrict__ ctok, float* __restrict__ cwt) {
  __shared__ int po[33];
  __shared__ int cnt[E_N];
  int tid = threadIdx.x;
  if (tid == 0) {
    int nt = 0, base = 0;
    for (int e = 0; e < E_N; ++e) {
      int c = counts[e];
      cnt[e] = c;
      po[e] = base;
      int tiles = (c + 127) >> 7;
      for (int tt = 0; tt < tiles; ++tt) { mt_e[nt] = e; mt_sb[nt] = base + tt * 128; ++nt; }
      base += tiles * 128;
    }
    po[E_N] = base;
    *nt_total = nt;
  }
  __syncthreads();
  for (int e = 0; e < E_N; ++e) {
    int b = po[e], c = cnt[e], cap = po[e + 1] - b;
    for (int i = tid; i < cap; i += 256) {
      if (i < c) { ctok[b + i] = ti_list[e * T_N + i]; cwt[b + i] = wt_list[e * T_N + i]; }
      else { ctok[b + i] = -1; cwt[b + i] = 0.f; }
    }
  }
}

// ---------------- fused gate+up GEMM: H = silu(X W1^T) * (X W3^T) ----------------
// 128x128 block tile, 4 waves as 2x2, each wave 64x64 via 4x4 16x16 fragments.
__global__ __launch_bounds__(256, 2) void up_gate_kernel(
    const void* __restrict__ X,
    const void* __restrict__ Wg, const void* __restrict__ Wu,
    const int* __restrict__ mode,
    const int* __restrict__ ctok, const int* __restrict__ mt_e,
    const int* __restrict__ mt_sb, const int* __restrict__ nt_total,
    unsigned short* __restrict__ H, int shared_mode) {
  __shared__ __align__(16) unsigned short Xs[128][72];
  __shared__ __align__(16) unsigned short Gs[128][72];
  __shared__ __align__(16) unsigned short Us[128][72];
  __shared__ int tokrow[128];

  int e, sb;
  if (shared_mode) { e = 0; sb = blockIdx.x * 128; }
  else {
    if ((int)blockIdx.x >= *nt_total) return;
    e = mt_e[blockIdx.x]; sb = mt_sb[blockIdx.x];
  }
  const int m = *mode;
  int tid = threadIdx.x;
  if (tid < 128) {
    int tk;
    if (shared_mode) tk = sb + tid;
    else { int raw = ctok[sb + tid]; tk = (raw >= 0) ? (raw >> 1) : -1; }
    tokrow[tid] = tk;
  }
  __syncthreads();

  const int n0 = blockIdx.y * 128;

  f32x4 accg[4][4], accu[4][4];
#pragma unroll
  for (int i = 0; i < 4; ++i)
#pragma unroll
    for (int j = 0; j < 4; ++j) { accg[i][j] = (f32x4)0.f; accu[i][j] = (f32x4)0.f; }

  const int w = tid >> 6, lane = tid & 63;
  const int wr = w >> 1, wc = w & 1;
  const int m16 = lane & 15, q = lane >> 4;
  const int lr = tid >> 3;          // 0..31
  const int lc = (tid & 7) * 8;     // 0..56

  for (int k0 = 0; k0 < D_N; k0 += 64) {
#pragma unroll
    for (int p = 0; p < 4; ++p) {
      int r = lr + p * 32;
      int tk = tokrow[r];
      uint4 v = {0u, 0u, 0u, 0u};
      if (tk >= 0) v = load8_as_bf16(X, (size_t)tk * D_N + k0 + lc, m);
      *(uint4*)&Xs[r][lc] = v;
      size_t wrow = (size_t)e * F_N + n0 + r;
      *(uint4*)&Gs[r][lc] = load8_as_bf16(Wg, wrow * D_N + k0 + lc, m);
      *(uint4*)&Us[r][lc] = load8_as_bf16(Wu, wrow * D_N + k0 + lc, m);
    }
    __syncthreads();
#pragma unroll
    for (int kk = 0; kk < 64; kk += 32) {
      short8 a[4];
#pragma unroll
      for (int mi = 0; mi < 4; ++mi)
        a[mi] = *(const short8*)&Xs[wr * 64 + mi * 16 + m16][kk + q * 8];
#pragma unroll
      for (int ni = 0; ni < 4; ++ni) {
        short8 bg = *(const short8*)&Gs[wc * 64 + ni * 16 + m16][kk + q * 8];
        short8 bu = *(const short8*)&Us[wc * 64 + ni * 16 + m16][kk + q * 8];
#pragma unroll
        for (int mi = 0; mi < 4; ++mi) {
          accg[mi][ni] = __builtin_amdgcn_mfma_f32_16x16x32_bf16(a[mi], bg, accg[mi][ni], 0, 0, 0);
          accu[mi][ni] = __builtin_amdgcn_mfma_f32_16x16x32_bf16(a[mi], bu, accu[mi][ni], 0, 0, 0);
        }
      }
    }
    __syncthreads();
  }
#pragma unroll
  for (int mi = 0; mi < 4; ++mi) {
#pragma unroll
    for (int ni = 0; ni < 4; ++ni) {
#pragma unroll
      for (int r = 0; r < 4; ++r) {
        float g = accg[mi][ni][r], u = accu[mi][ni][r];
        float h = (g / (1.f + __expf(-g))) * u;
        int mloc = wr * 64 + mi * 16 + q * 4 + r;
        int f = n0 + wc * 64 + ni * 16 + m16;
        H[(size_t)(sb + mloc) * F_N + f] = f2bf(h);
      }
    }
  }
}

// ---------------- routed down GEMM + weighted scatter ----------------
__global__ __launch_bounds__(256, 2) void down_routed_kernel(
    const unsigned short* __restrict__ H, const void* __restrict__ W2,
    const int* __restrict__ mode,
    const int* __restrict__ ctok, const float* __restrict__ cwt,
    const int* __restrict__ mt_e, const int* __restrict__ mt_sb,
    const int* __restrict__ nt_total,
    float* __restrict__ acc0, float* __restrict__ acc1) {
  __shared__ __align__(16) unsigned short Hs[128][72];
  __shared__ __align__(16) unsigned short Ws[128][72];
  if ((int)blockIdx.x >= *nt_total) return;
  int e = mt_e[blockIdx.x], sb = mt_sb[blockIdx.x];
  const int m = *mode;
  const int n0 = blockIdx.y * 128;

  f32x4 acc[4][4];
#pragma unroll
  for (int i = 0; i < 4; ++i)
#pragma unroll
    for (int j = 0; j < 4; ++j) acc[i][j] = (f32x4)0.f;

  int tid = threadIdx.x;
  const int w = tid >> 6, lane = tid & 63;
  const int wr = w >> 1, wc = w & 1;
  const int m16 = lane & 15, q = lane >> 4;
  const int lr = tid >> 3, lc = (tid & 7) * 8;

  for (int k0 = 0; k0 < F_N; k0 += 64) {
#pragma unroll
    for (int p = 0; p < 4; ++p) {
      int r = lr + p * 32;
      *(uint4*)&Hs[r][lc] = *(const uint4*)(H + (size_t)(sb + r) * F_N + k0 + lc);
      size_t wrow = (size_t)e * D_N + n0 + r;
      *(uint4*)&Ws[r][lc] = load8_as_bf16(W2, wrow * F_N + k0 + lc, m);
    }
    __syncthreads();
#pragma unroll
    for (int kk = 0; kk < 64; kk += 32) {
      short8 a[4];
#pragma unroll
      for (int mi = 0; mi < 4; ++mi)
        a[mi] = *(const short8*)&Hs[wr * 64 + mi * 16 + m16][kk + q * 8];
#pragma unroll
      for (int ni = 0; ni < 4; ++ni) {
        short8 b = *(const short8*)&Ws[wc * 64 + ni * 16 + m16][kk + q * 8];
#pragma unroll
        for (int mi = 0; mi < 4; ++mi)
          acc[mi][ni] = __builtin_amdgcn_mfma_f32_16x16x32_bf16(a[mi], b, acc[mi][ni], 0, 0, 0);
      }
    }
    __syncthreads();
  }
#pragma unroll
  for (int mi = 0; mi < 4; ++mi) {
#pragma unroll
    for (int ni = 0; ni < 4; ++ni) {
#pragma unroll
      for (int r = 0; r < 4; ++r) {
        int mloc = wr * 64 + mi * 16 + q * 4 + r;
        int slot = sb + mloc;
        int raw = ctok[slot];
        if (raw >= 0) {
          int t = raw >> 1;
          float v = acc[mi][ni][r] * cwt[slot];
          float* A = (raw & 1) ? acc1 : acc0;
          A[(size_t)t * D_N + n0 + wc * 64 + ni * 16 + m16] = v;
        }
      }
    }
  }
}

// ---------------- shared down GEMM + final combine ----------------
__global__ __launch_bounds__(256, 2) void down_shared_final_kernel(
    const unsigned short* __restrict__ Hsg, const void* __restrict__ SW2,
    const int* __restrict__ mode,
    const float* __restrict__ acc0, const float* __restrict__ acc1,
    void* __restrict__ out) {
  __shared__ __align__(16) unsigned short Hs[128][72];
  __shared__ __align__(16) unsigned short Ws[128][72];
  const int t0 = blockIdx.x * 128;
  const int n0 = blockIdx.y * 128;
  const int m = *mode;

  f32x4 acc[4][4];
#pragma unroll
  for (int i = 0; i < 4; ++i)
#pragma unroll
    for (int j = 0; j < 4; ++j) acc[i][j] = (f32x4)0.f;

  int tid = threadIdx.x;
  const int w = tid >> 6, lane = tid & 63;
  const int wr = w >> 1, wc = w & 1;
  const int m16 = lane & 15, q = lane >> 4;
  const int lr = tid >> 3, lc = (tid & 7) * 8;

  for (int k0 = 0; k0 < F_N; k0 += 64) {
#pragma unroll
    for (int p = 0; p < 4; ++p) {
      int r = lr + p * 32;
      *(uint4*)&Hs[r][lc] = *(const uint4*)(Hsg + (size_t)(t0 + r) * F_N + k0 + lc);
      *(uint4*)&Ws[r][lc] = load8_as_bf16(SW2, (size_t)(n0 + r) * F_N + k0 + lc, m);
    }
    __syncthreads();
#pragma unroll
    for (int kk = 0; kk < 64; kk += 32) {
      short8 a[4];
#pragma unroll
      for (int mi = 0; mi < 4; ++mi)
        a[mi] = *(const short8*)&Hs[wr * 64 + mi * 16 + m16][kk + q * 8];
#pragma unroll
      for (int ni = 0; ni < 4; ++ni) {
        short8 b = *(const short8*)&Ws[wc * 64 + ni * 16 + m16][kk + q * 8];
#pragma unroll
        for (int mi = 0; mi < 4; ++mi)
          acc[mi][ni] = __builtin_amdgcn_mfma_f32_16x16x32_bf16(a[mi], b, acc[mi][ni], 0, 0, 0);
      }
    }
    __syncthreads();
  }
#pragma unroll
  for (int mi = 0; mi < 4; ++mi) {
#pragma unroll
    for (int ni = 0; ni < 4; ++ni) {
#pragma unroll
      for (int r = 0; r < 4; ++r) {
        int mloc = wr * 64 + mi * 16 + q * 4 + r;
        int t = t0 + mloc;
        int c = n0 + wc * 64 + ni * 16 + m16;
        size_t o = (size_t)t * D_N + c;
        float v = acc[mi][ni][r] + acc0[o] + acc1[o];
        if (m) ((float*)out)[o] = v;
        else   ((unsigned short*)out)[o] = f2bf(v);
      }
    }
  }
}

extern "C" void kernel_launch(void* const* d_in, const int* in_sizes, int n_in,
                              void* d_out, int out_size, void* d_ws, size_t ws_size,
                              hipStream_t stream) {
  const void* X   = d_in[0];
  const void* GW  = d_in[1];
  const void* W1  = d_in[2];
  const void* W2  = d_in[3];
  const void* W3  = d_in[4];
  const void* SW1 = d_in[5];
  const void* SW2 = d_in[6];
  const void* SW3 = d_in[7];
  (void)SW3;

  char* w = (char*)d_ws;
  int*   head     = (int*)(w + 0);            // counts[32], nt_total@32, mode@48
  int*   counts   = head;
  int*   nt_total = head + 32;
  int*   mode     = head + 48;
  int*   mt_e     = (int*)(w + 512);          // up to 64 tiles
  int*   mt_sb    = (int*)(w + 1024);
  int*   ti_list  = (int*)(w + 4096);         // 32*2048 ints   = 256 KB
  float* wt_list  = (float*)(w + 266240);     // 32*2048 floats = 256 KB
  int*   ctok     = (int*)(w + 528384);       // 8192 ints
  float* cwt      = (float*)(w + 561152);     // 8192 floats
  unsigned short* Hr = (unsigned short*)(w + (1u << 20));   // 8192x1024 bf16 = 16 MB
  unsigned short* Hs = (unsigned short*)(w + 17825792u);    // 2048x1024 bf16 = 4 MB
  float* acc0 = (float*)(w + 22020096u);                    // 2048x2048 f32 = 16 MB
  float* acc1 = (float*)(w + 38797312u);                    // 2048x2048 f32 = 16 MB

  init_kernel<<<1, 64, 0, stream>>>(X, head);
  router_kernel<<<T_N, 64, 0, stream>>>(X, GW, mode, counts, ti_list, wt_list);
  compact_kernel<<<1, 256, 0, stream>>>(counts, ti_list, wt_list, mt_e, mt_sb, nt_total, ctok, cwt);
  up_gate_kernel<<<dim3(64, F_N / 128), 256, 0, stream>>>(X, W1, W3, mode, ctok, mt_e, mt_sb, nt_total, Hr, 0);
  up_gate_kernel<<<dim3(T_N / 128, F_N / 128), 256, 0, stream>>>(X, SW1, SW3, mode, ctok, mt_e, mt_sb, nt_total, Hs, 1);
  down_routed_kernel<<<dim3(64, D_N / 128), 256, 0, stream>>>(Hr, W2, mode, ctok, cwt, mt_e, mt_sb, nt_total, acc0, acc1);
  down_shared_final_kernel<<<dim3(T_N / 128, D_N / 128), 256, 0, stream>>>(Hs, SW2, mode, acc0, acc1, d_out);
}